// Round 20
// baseline (144.168 us; speedup 1.0000x reference)
//
#include <hip/hip_runtime.h>

#define BB 16
#define LL 200
#define HID 128
#define NH 4
#define DH 32
#define IH 96
#define NROW (BB*LL)          // 3200
#define LNEPS 1e-8f

typedef unsigned short ushort_t;
typedef __fp16   h2s __attribute__((ext_vector_type(2)));   // builtin I/O type
typedef _Float16 h2a __attribute__((ext_vector_type(2)));   // arithmetic type

union U4 { ushort4 u; h2s h[2]; };

__device__ __forceinline__ h2a toa(h2s x) { return __builtin_bit_cast(h2a, x); }

__device__ __forceinline__ float embed_val(int id, int col,
                                           const int* __restrict__ meta,
                                           const float* __restrict__ iW,
                                           const float* __restrict__ bW,
                                           const float* __restrict__ cW)
{
    float v;
    if (col < IH)           v = iW[(size_t)id*IH + col];
    else if (col < IH + 16) v = bW[meta[2*id]   *16 + (col-IH)];
    else                    v = cW[meta[2*id+1] *16 + (col-IH-16)];
    return v;
}

__device__ __forceinline__ ushort_t f2h(float f) {   // fp32 -> fp16 (RTZ)
    union { h2s h; ushort_t u[2]; } c;
    c.h = __builtin_amdgcn_cvt_pkrtz(f, f);
    return c.u[0];
}

// ---------------- K1: embed + attn-LN(0) + Q/K/V GEMVs(0), 8 rows/block
//                    blocks 0..256 also convert one row of tK/tV to fp16
__global__ __launch_bounds__(512) void k_emb_lnqkv(
    const int* __restrict__ logs, const int* __restrict__ meta,
    const float* __restrict__ iW, const float* __restrict__ bW,
    const float* __restrict__ cW,
    const float* __restrict__ lns, const float* __restrict__ lnb,
    const float* __restrict__ Qw, const float* __restrict__ Qb,
    const float* __restrict__ Kw, const float* __restrict__ Kb,
    const float* __restrict__ Vw, const float* __restrict__ Vb,
    const float* __restrict__ posK, const float* __restrict__ posV,
    const float* __restrict__ tK, const float* __restrict__ tV,
    ushort_t* __restrict__ tkh, ushort_t* __restrict__ tvh,
    float* __restrict__ Qn, float* __restrict__ qbuf,
    ushort_t* __restrict__ kbh, ushort_t* __restrict__ vbh)
{
    __shared__ float xs[8][HID];
    __shared__ float qn[8][HID];
    __shared__ float red[4][HID];
    int tid = threadIdx.x;
    int g = tid >> 7, col = tid & 127;
    int r0 = blockIdx.x * 8;

    // folded table conversion (one t-row per block, first 257 blocks)
    if (blockIdx.x < 257) {
        int t = blockIdx.x;
        if (tid < 128)      tkh[(size_t)t*HID + tid]       = f2h(tK[(size_t)t*HID + tid]);
        else if (tid < 256) tvh[(size_t)t*HID + (tid-128)] = f2h(tV[(size_t)t*HID + (tid-128)]);
    }

    #pragma unroll
    for (int p = 0; p < 2; ++p) {
        int rr = g + p*4;
        int row = r0 + rr;
        int id = logs[row];
        float x = (id == 0) ? 0.f : embed_val(id, col, meta, iW, bW, cW) * 9.797958971132712f;
        xs[rr][col] = x;
        red[g][col] = x;
        __syncthreads();
        for (int off = 64; off; off >>= 1) { if (col < off) red[g][col] += red[g][col+off]; __syncthreads(); }
        float mu = red[g][0] * (1.f/HID);
        __syncthreads();
        float c = x - mu;
        red[g][col] = c*c; __syncthreads();
        for (int off = 64; off; off >>= 1) { if (col < off) red[g][col] += red[g][col+off]; __syncthreads(); }
        float ln = c * rsqrtf(red[g][0]*(1.f/HID) + LNEPS) * lns[col] + lnb[col];
        qn[rr][col] = ln;
        Qn[(size_t)row*HID + col] = ln;
        __syncthreads();
    }

    int rA = 2*g, rB = 2*g + 1;
    float aq0 = Qb[col], aq1 = aq0;
    float ak0 = Kb[col], ak1 = ak0;
    float av0 = Vb[col], av1 = av0;
    const float* q0 = qn[rA]; const float* q1 = qn[rB];
    const float* x0 = xs[rA]; const float* x1 = xs[rB];
    #pragma unroll 8
    for (int kk = 0; kk < HID; ++kk) {
        float wq = Qw[kk*HID + col];
        float wk = Kw[kk*HID + col];
        float wv = Vw[kk*HID + col];
        aq0 += q0[kk]*wq; aq1 += q1[kk]*wq;
        ak0 += x0[kk]*wk; ak1 += x1[kk]*wk;
        av0 += x0[kk]*wv; av1 += x1[kk]*wv;
    }
    int rowA = r0 + rA, rowB = r0 + rB;
    int lA = rowA % LL, lB = rowB % LL;
    qbuf[(size_t)rowA*HID + col] = aq0;
    qbuf[(size_t)rowB*HID + col] = aq1;
    kbh[(size_t)rowA*HID + col] = f2h(ak0 + posK[lA*HID + col]);
    kbh[(size_t)rowB*HID + col] = f2h(ak1 + posK[lB*HID + col]);
    vbh[(size_t)rowA*HID + col] = f2h(av0 + posV[lA*HID + col]);
    vbh[(size_t)rowB*HID + col] = f2h(av1 + posV[lB*HID + col]);
}

// ---------------- attention: block=(h,ip,bh) handles rows i=ip and i=199-ip
//                  (uniform 201 j's per block); 8 waves = 8 batches; fp16, dot2
__global__ __launch_bounds__(512) void k_attn(
    const float*   __restrict__ q,
    const ushort4* __restrict__ kph,  // fp16 k+posK, [NROW][32] as ushort4
    const ushort4* __restrict__ vph,  // fp16 v+posV
    const float4*  __restrict__ Qn4,
    const ushort4* __restrict__ tkh4, // fp16 tables [257][32] as ushort4
    const ushort4* __restrict__ tvh4,
    const int* __restrict__ tmat, const int* __restrict__ logs,
    float4* __restrict__ out4)
{
    __shared__ ushort4 tk_lds[257*8];   // ~16.45 KiB
    __shared__ ushort4 tv_lds[257*8];   // (total ~32.9 KiB)

    int bid = blockIdx.x;
    int h   = bid & 3;
    int bh  = (bid >> 2) & 1;
    int ip  = bid >> 3;                 // 0..99
    int tid = threadIdx.x;

    for (int e = tid; e < 257*8; e += 512) {
        int t = e >> 3, s = e & 7;
        tk_lds[t*8 + s] = tkh4[(size_t)t*32 + h*8 + s];
        tv_lds[t*8 + s] = tvh4[(size_t)t*32 + h*8 + s];
    }
    __syncthreads();

    int b = __builtin_amdgcn_readfirstlane(tid >> 6) + bh*8;
    int lane = tid & 63;
    int g8 = lane & 56;        // j-octet offset of this lane's group
    int d4 = lane & 7;         // ushort4-slice index within the 32-wide head dim
    int jc = lane >> 3;

    #pragma unroll
    for (int rp = 0; rp < 2; ++rp) {
        int i = rp ? (199 - ip) : ip;
        int row = b*LL + i;
        int valid = (logs[row] != 0);
        int nj = valid ? (i + 1) : LL;

        float4 qq = ((const float4*)q)[(size_t)row*32 + h*8 + d4];
        h2s q01 = __builtin_amdgcn_cvt_pkrtz(qq.x, qq.y);
        h2s q23 = __builtin_amdgcn_cvt_pkrtz(qq.z, qq.w);

        int tsv[4];
        #pragma unroll
        for (int c = 0; c < 4; ++c) {
            int j = c*64 + lane;
            tsv[c] = (j < nj) ? tmat[(size_t)row*LL + j] : 0;
        }

        // scores (transposed): group handles j = c*64 + g8 + qi; chained dot2
        float ev[4];
        #pragma unroll
        for (int c = 0; c < 4; ++c) {
            float s0 = -INFINITY;
            if (valid) {
                int jbase = c*64 + g8;
                if (jbase < nj) {
                    #pragma unroll
                    for (int qi = 0; qi < 8; ++qi) {
                        int j = jbase + qi;
                        bool ok = (j < nj);              // uniform within the 8-lane group
                        int t = __shfl(tsv[c], g8 + qi);
                        float part = 0.f;
                        if (ok) {
                            U4 kr; kr.u = kph[((size_t)(b*LL + j))*32 + h*8 + d4];
                            U4 tk; tk.u = tk_lds[t*8 + d4];
                            part = __builtin_amdgcn_fdot2(q01, kr.h[0], 0.f,  false);
                            part = __builtin_amdgcn_fdot2(q23, kr.h[1], part, false);
                            part = __builtin_amdgcn_fdot2(q01, tk.h[0], part, false);
                            part = __builtin_amdgcn_fdot2(q23, tk.h[1], part, false);
                        }
                        part += __shfl_xor(part, 1);
                        part += __shfl_xor(part, 2);
                        part += __shfl_xor(part, 4);
                        if (qi == d4 && ok) s0 = part * 0.17677669529663687f;
                    }
                }
            } else {
                if (c*64 + lane < nj) s0 = 0.f;          // invalid row -> uniform softmax
            }
            ev[c] = s0;
        }

        // softmax (in-register, wave-level)
        float m = fmaxf(fmaxf(ev[0], ev[1]), fmaxf(ev[2], ev[3]));
        #pragma unroll
        for (int off = 32; off; off >>= 1) m = fmaxf(m, __shfl_xor(m, off));
        float ssum = 0.f;
        #pragma unroll
        for (int c = 0; c < 4; ++c) {
            int j = c*64 + lane;
            float e = (j < nj) ? __expf(ev[c] - m) : 0.f;
            ev[c] = e; ssum += e;
        }
        #pragma unroll
        for (int off = 32; off; off >>= 1) ssum += __shfl_xor(ssum, off);
        float inv = 1.f / ssum;

        // PV: lanes = (jc in 0..7) x (d4 in 0..7); packed fp16 add, fp32 accumulate
        float4 acc = {0.f, 0.f, 0.f, 0.f};
        #pragma unroll
        for (int c = 0; c < 4; ++c) {
            int jlo = c*64;
            int jhi = (jlo + 64 < nj) ? (jlo + 64) : nj;
            for (int jj = jlo; jj < jhi; jj += 8) {
                int j = jj + jc;
                float a  = __shfl(ev[c],  j & 63);
                int  tsj = __shfl(tsv[c], j & 63);
                if (j < jhi) {
                    U4 vr; vr.u = vph[((size_t)(b*LL + j))*32 + h*8 + d4];
                    U4 tv; tv.u = tv_lds[tsj*8 + d4];
                    h2a s01 = toa(vr.h[0]) + toa(tv.h[0]);
                    h2a s23 = toa(vr.h[1]) + toa(tv.h[1]);
                    acc.x += a * (float)s01[0];
                    acc.y += a * (float)s01[1];
                    acc.z += a * (float)s23[0];
                    acc.w += a * (float)s23[1];
                }
            }
        }
        #pragma unroll
        for (int off = 8; off < 64; off <<= 1) {
            acc.x += __shfl_xor(acc.x, off);
            acc.y += __shfl_xor(acc.y, off);
            acc.z += __shfl_xor(acc.z, off);
            acc.w += __shfl_xor(acc.w, off);
        }
        if (jc == 0) {
            float4 qn = Qn4[(size_t)row*32 + h*8 + d4];
            float4 o;
            o.x = qn.x + acc.x*inv;
            o.y = qn.y + acc.y*inv;
            o.z = qn.z + acc.z*inv;
            o.w = qn.w + acc.w*inv;
            out4[(size_t)row*32 + h*8 + d4] = o;
        }
    }
}

// ---------------- fwd-LN + FFN + residual + mask, 8 rows/block (in-place on seqs)
__global__ __launch_bounds__(512) void k_ffn(
    const float* __restrict__ seqs_in,
    const float* __restrict__ lns, const float* __restrict__ lnb,
    const float* __restrict__ c1w, const float* __restrict__ c1b,
    const float* __restrict__ c2w, const float* __restrict__ c2b,
    const int* __restrict__ logs,
    float* __restrict__ seqs_out)
{
    __shared__ float xs[8][HID];
    __shared__ float h1[8][HID];
    __shared__ float red[4][HID];
    int tid = threadIdx.x;
    int g = tid >> 7, col = tid & 127;
    int r0 = blockIdx.x * 8;

    #pragma unroll
    for (int p = 0; p < 2; ++p) {
        int rr = g + p*4;
        int row = r0 + rr;
        float x = seqs_in[(size_t)row*HID + col];
        red[g][col] = x;
        __syncthreads();
        for (int off = 64; off; off >>= 1) { if (col < off) red[g][col] += red[g][col+off]; __syncthreads(); }
        float mu = red[g][0] * (1.f/HID);
        __syncthreads();
        float c = x - mu;
        red[g][col] = c*c; __syncthreads();
        for (int off = 64; off; off >>= 1) { if (col < off) red[g][col] += red[g][col+off]; __syncthreads(); }
        xs[rr][col] = c * rsqrtf(red[g][0]*(1.f/HID) + LNEPS) * lns[col] + lnb[col];
        __syncthreads();
    }

    int rA = 2*g, rB = 2*g + 1;
    {
        float a0 = c1b[col], a1 = a0;
        const float* x0 = xs[rA]; const float* x1 = xs[rB];
        #pragma unroll 8
        for (int kk = 0; kk < HID; ++kk) {
            float w = c1w[kk*HID + col];
            a0 += x0[kk]*w; a1 += x1[kk]*w;
        }
        h1[rA][col] = fmaxf(a0, 0.f);
        h1[rB][col] = fmaxf(a1, 0.f);
    }
    __syncthreads();

    {
        float a0 = c2b[col], a1 = a0;
        const float* y0 = h1[rA]; const float* y1 = h1[rB];
        #pragma unroll 8
        for (int kk = 0; kk < HID; ++kk) {
            float w = c2w[kk*HID + col];
            a0 += y0[kk]*w; a1 += y1[kk]*w;
        }
        int rowA = r0 + rA, rowB = r0 + rB;
        float o0 = xs[rA][col] + a0;
        float o1 = xs[rB][col] + a1;
        if (logs[rowA] == 0) o0 = 0.f;
        if (logs[rowB] == 0) o1 = 0.f;
        seqs_out[(size_t)rowA*HID + col] = o0;
        seqs_out[(size_t)rowB*HID + col] = o1;
    }
}

// ---------------- attn-LN + Q/K/V GEMVs, 8 rows/block
__global__ __launch_bounds__(512) void k_lnqkv(
    const float* __restrict__ seqs,
    const float* __restrict__ lns, const float* __restrict__ lnb,
    const float* __restrict__ Qw, const float* __restrict__ Qb,
    const float* __restrict__ Kw, const float* __restrict__ Kb,
    const float* __restrict__ Vw, const float* __restrict__ Vb,
    const float* __restrict__ posK, const float* __restrict__ posV,
    float* __restrict__ Qn, float* __restrict__ qbuf,
    ushort_t* __restrict__ kbh, ushort_t* __restrict__ vbh)
{
    __shared__ float xs[8][HID];
    __shared__ float qn[8][HID];
    __shared__ float red[4][HID];
    int tid = threadIdx.x;
    int g = tid >> 7, col = tid & 127;
    int r0 = blockIdx.x * 8;

    #pragma unroll
    for (int p = 0; p < 2; ++p) {
        int rr = g + p*4;
        int row = r0 + rr;
        float x = seqs[(size_t)row*HID + col];
        xs[rr][col] = x;
        red[g][col] = x;
        __syncthreads();
        for (int off = 64; off; off >>= 1) { if (col < off) red[g][col] += red[g][col+off]; __syncthreads(); }
        float mu = red[g][0] * (1.f/HID);
        __syncthreads();
        float c = x - mu;
        red[g][col] = c*c; __syncthreads();
        for (int off = 64; off; off >>= 1) { if (col < off) red[g][col] += red[g][col+off]; __syncthreads(); }
        float ln = c * rsqrtf(red[g][0]*(1.f/HID) + LNEPS) * lns[col] + lnb[col];
        qn[rr][col] = ln;
        Qn[(size_t)row*HID + col] = ln;
        __syncthreads();
    }

    int rA = 2*g, rB = 2*g + 1;
    float aq0 = Qb[col], aq1 = aq0;
    float ak0 = Kb[col], ak1 = ak0;
    float av0 = Vb[col], av1 = av0;
    const float* q0 = qn[rA]; const float* q1 = qn[rB];
    const float* x0 = xs[rA]; const float* x1 = xs[rB];
    #pragma unroll 8
    for (int kk = 0; kk < HID; ++kk) {
        float wq = Qw[kk*HID + col];
        float wk = Kw[kk*HID + col];
        float wv = Vw[kk*HID + col];
        aq0 += q0[kk]*wq; aq1 += q1[kk]*wq;
        ak0 += x0[kk]*wk; ak1 += x1[kk]*wk;
        av0 += x0[kk]*wv; av1 += x1[kk]*wv;
    }
    int rowA = r0 + rA, rowB = r0 + rB;
    int lA = rowA % LL, lB = rowB % LL;
    qbuf[(size_t)rowA*HID + col] = aq0;
    qbuf[(size_t)rowB*HID + col] = aq1;
    kbh[(size_t)rowA*HID + col] = f2h(ak0 + posK[lA*HID + col]);
    kbh[(size_t)rowB*HID + col] = f2h(ak1 + posK[lB*HID + col]);
    vbh[(size_t)rowA*HID + col] = f2h(av0 + posV[lA*HID + col]);
    vbh[(size_t)rowB*HID + col] = f2h(av1 + posV[lB*HID + col]);
}

// ---------------- K3: FFN(1) + last-LN + pos/neg logits, 8 rows/block
__global__ __launch_bounds__(512) void k_ffn_logits(
    const float* __restrict__ seqs_in,
    const float* __restrict__ flns, const float* __restrict__ flnb,
    const float* __restrict__ c1w, const float* __restrict__ c1b,
    const float* __restrict__ c2w, const float* __restrict__ c2b,
    const int* __restrict__ logs,
    const float* __restrict__ lls, const float* __restrict__ llb,
    const int* __restrict__ pos, const int* __restrict__ neg,
    const int* __restrict__ meta,
    const float* __restrict__ iW, const float* __restrict__ bW,
    const float* __restrict__ cW,
    float* __restrict__ out)
{
    __shared__ float xs[8][HID];
    __shared__ float h1[8][HID];
    __shared__ float red[4][HID];
    __shared__ float sx[8][HID];
    int tid = threadIdx.x;
    int g = tid >> 7, col = tid & 127;
    int r0 = blockIdx.x * 8;

    #pragma unroll
    for (int p = 0; p < 2; ++p) {
        int rr = g + p*4;
        int row = r0 + rr;
        float x = seqs_in[(size_t)row*HID + col];
        red[g][col] = x;
        __syncthreads();
        for (int off = 64; off; off >>= 1) { if (col < off) red[g][col] += red[g][col+off]; __syncthreads(); }
        float mu = red[g][0] * (1.f/HID);
        __syncthreads();
        float c = x - mu;
        red[g][col] = c*c; __syncthreads();
        for (int off = 64; off; off >>= 1) { if (col < off) red[g][col] += red[g][col+off]; __syncthreads(); }
        xs[rr][col] = c * rsqrtf(red[g][0]*(1.f/HID) + LNEPS) * flns[col] + flnb[col];
        __syncthreads();
    }

    int rA = 2*g, rB = 2*g + 1;
    {
        float a0 = c1b[col], a1 = a0;
        const float* x0 = xs[rA]; const float* x1 = xs[rB];
        #pragma unroll 8
        for (int kk = 0; kk < HID; ++kk) {
            float w = c1w[kk*HID + col];
            a0 += x0[kk]*w; a1 += x1[kk]*w;
        }
        h1[rA][col] = fmaxf(a0, 0.f);
        h1[rB][col] = fmaxf(a1, 0.f);
    }
    __syncthreads();
    {
        float a0 = c2b[col], a1 = a0;
        const float* y0 = h1[rA]; const float* y1 = h1[rB];
        #pragma unroll 8
        for (int kk = 0; kk < HID; ++kk) {
            float w = c2w[kk*HID + col];
            a0 += y0[kk]*w; a1 += y1[kk]*w;
        }
        int rowA = r0 + rA, rowB = r0 + rB;
        float o0 = xs[rA][col] + a0;
        float o1 = xs[rB][col] + a1;
        if (logs[rowA] == 0) o0 = 0.f;
        if (logs[rowB] == 0) o1 = 0.f;
        sx[rA][col] = o0;
        sx[rB][col] = o1;
    }
    __syncthreads();

    #pragma unroll
    for (int p = 0; p < 2; ++p) {
        int rr = g + p*4;
        int row = r0 + rr;
        float x = sx[rr][col];
        red[g][col] = x;
        __syncthreads();
        for (int off = 64; off; off >>= 1) { if (col < off) red[g][col] += red[g][col+off]; __syncthreads(); }
        float mu = red[g][0] * (1.f/HID);
        __syncthreads();
        float c = x - mu;
        red[g][col] = c*c; __syncthreads();
        for (int off = 64; off; off >>= 1) { if (col < off) red[g][col] += red[g][col+off]; __syncthreads(); }
        float f = c * rsqrtf(red[g][0]*(1.f/HID) + LNEPS) * lls[col] + llb[col];
        __syncthreads();

        int pid = pos[row];
        float e = embed_val(pid, col, meta, iW, bW, cW);
        red[g][col] = f * e; __syncthreads();
        for (int off = 64; off; off >>= 1) { if (col < off) red[g][col] += red[g][col+off]; __syncthreads(); }
        if (col == 0) out[row] = red[g][0];
        __syncthreads();

        int nid = neg[row];
        e = embed_val(nid, col, meta, iW, bW, cW);
        red[g][col] = f * e; __syncthreads();
        for (int off = 64; off; off >>= 1) { if (col < off) red[g][col] += red[g][col+off]; __syncthreads(); }
        if (col == 0) out[NROW + row] = red[g][0];
        __syncthreads();
    }
}

extern "C" void kernel_launch(void* const* d_in, const int* in_sizes, int n_in,
                              void* d_out, int out_size, void* d_ws, size_t ws_size,
                              hipStream_t stream)
{
    const int*  logs = (const int*)d_in[1];
    const int*  tmat = (const int*)d_in[2];
    const int*  pos  = (const int*)d_in[3];
    const int*  neg  = (const int*)d_in[4];
    const int*  meta = (const int*)d_in[5];
    const float* iW   = (const float*)d_in[6];
    const float* bW   = (const float*)d_in[7];
    const float* cW   = (const float*)d_in[8];
    const float* posK = (const float*)d_in[9];
    const float* posV = (const float*)d_in[10];
    const float* tK   = (const float*)d_in[11];
    const float* tV   = (const float*)d_in[12];
    const float* attn_s = (const float*)d_in[13];
    const float* attn_b = (const float*)d_in[14];
    const float* Qw = (const float*)d_in[15];
    const float* Qb = (const float*)d_in[16];
    const float* Kw = (const float*)d_in[17];
    const float* Kb = (const float*)d_in[18];
    const float* Vw = (const float*)d_in[19];
    const float* Vb = (const float*)d_in[20];
    const float* fwd_s = (const float*)d_in[21];
    const float* fwd_b = (const float*)d_in[22];
    const float* c1w = (const float*)d_in[23];
    const float* c1b = (const float*)d_in[24];
    const float* c2w = (const float*)d_in[25];
    const float* c2b = (const float*)d_in[26];
    const float* lls = (const float*)d_in[27];
    const float* llb = (const float*)d_in[28];

    const size_t RC = (size_t)NROW * HID;
    float* seqs = (float*)d_ws;
    float* Qn   = seqs + RC;
    float* qbuf = Qn   + RC;
    ushort_t* kbh = (ushort_t*)(qbuf + RC);            // [NROW][128] fp16
    ushort_t* vbh = kbh + RC;
    ushort_t* tkh = vbh + RC;                          // [257][128] fp16
    ushort_t* tvh = tkh + 257*HID;

    const size_t W = (size_t)HID * HID;

    // layer 0 (also converts tK/tV tables to fp16)
    k_emb_lnqkv<<<NROW/8, 512, 0, stream>>>(logs, meta, iW, bW, cW,
                                            attn_s, attn_b,
                                            Qw, Qb, Kw, Kb, Vw, Vb,
                                            posK, posV, tK, tV, tkh, tvh,
                                            Qn, qbuf, kbh, vbh);
    k_attn<<<NH*100*2, 512, 0, stream>>>(qbuf, (const ushort4*)kbh,
                                         (const ushort4*)vbh, (const float4*)Qn,
                                         (const ushort4*)tkh, (const ushort4*)tvh,
                                         tmat, logs, (float4*)seqs);
    k_ffn<<<NROW/8, 512, 0, stream>>>(seqs, fwd_s, fwd_b,
                                      c1w, c1b, c2w, c2b, logs, seqs);
    // layer 1
    k_lnqkv<<<NROW/8, 512, 0, stream>>>(seqs, attn_s + HID, attn_b + HID,
                                        Qw + W, Qb + HID, Kw + W, Kb + HID,
                                        Vw + W, Vb + HID,
                                        posK, posV, Qn, qbuf, kbh, vbh);
    k_attn<<<NH*100*2, 512, 0, stream>>>(qbuf, (const ushort4*)kbh,
                                         (const ushort4*)vbh, (const float4*)Qn,
                                         (const ushort4*)tkh, (const ushort4*)tvh,
                                         tmat, logs, (float4*)seqs);
    k_ffn_logits<<<NROW/8, 512, 0, stream>>>(seqs, fwd_s + HID, fwd_b + HID,
                                             c1w + W, c1b + HID, c2w + W, c2b + HID,
                                             logs, lls, llb, pos, neg, meta,
                                             iW, bW, cW, (float*)d_out);
}

// Round 21
// 137.291 us; speedup vs baseline: 1.0501x; 1.0501x over previous
//
#include <hip/hip_runtime.h>

#define BB 16
#define LL 200
#define HID 128
#define NH 4
#define DH 32
#define IH 96
#define NROW (BB*LL)          // 3200
#define LNEPS 1e-8f

typedef unsigned short ushort_t;
typedef __fp16   h2s __attribute__((ext_vector_type(2)));   // builtin I/O type
typedef _Float16 h2a __attribute__((ext_vector_type(2)));   // arithmetic type

union U4 { ushort4 u; h2s h[2]; };

__device__ __forceinline__ h2a toa(h2s x) { return __builtin_bit_cast(h2a, x); }

__device__ __forceinline__ float embed_val(int id, int col,
                                           const int* __restrict__ meta,
                                           const float* __restrict__ iW,
                                           const float* __restrict__ bW,
                                           const float* __restrict__ cW)
{
    float v;
    if (col < IH)           v = iW[(size_t)id*IH + col];
    else if (col < IH + 16) v = bW[meta[2*id]   *16 + (col-IH)];
    else                    v = cW[meta[2*id+1] *16 + (col-IH-16)];
    return v;
}

__device__ __forceinline__ ushort_t f2h(float f) {   // fp32 -> fp16 (RTZ)
    union { h2s h; ushort_t u[2]; } c;
    c.h = __builtin_amdgcn_cvt_pkrtz(f, f);
    return c.u[0];
}

// ---------------- K1: embed + attn-LN(0) + Q/K/V GEMVs(0), 8 rows/block
//                    blocks 0..256 also convert one row of tK/tV to fp16
__global__ __launch_bounds__(512) void k_emb_lnqkv(
    const int* __restrict__ logs, const int* __restrict__ meta,
    const float* __restrict__ iW, const float* __restrict__ bW,
    const float* __restrict__ cW,
    const float* __restrict__ lns, const float* __restrict__ lnb,
    const float* __restrict__ Qw, const float* __restrict__ Qb,
    const float* __restrict__ Kw, const float* __restrict__ Kb,
    const float* __restrict__ Vw, const float* __restrict__ Vb,
    const float* __restrict__ posK, const float* __restrict__ posV,
    const float* __restrict__ tK, const float* __restrict__ tV,
    ushort_t* __restrict__ tkh, ushort_t* __restrict__ tvh,
    float* __restrict__ Qn, float* __restrict__ qbuf,
    ushort_t* __restrict__ kbh, ushort_t* __restrict__ vbh)
{
    __shared__ float xs[8][HID];
    __shared__ float qn[8][HID];
    __shared__ float red[4][HID];
    int tid = threadIdx.x;
    int g = tid >> 7, col = tid & 127;
    int r0 = blockIdx.x * 8;

    // folded table conversion (one t-row per block, first 257 blocks)
    if (blockIdx.x < 257) {
        int t = blockIdx.x;
        if (tid < 128)      tkh[(size_t)t*HID + tid]       = f2h(tK[(size_t)t*HID + tid]);
        else if (tid < 256) tvh[(size_t)t*HID + (tid-128)] = f2h(tV[(size_t)t*HID + (tid-128)]);
    }

    #pragma unroll
    for (int p = 0; p < 2; ++p) {
        int rr = g + p*4;
        int row = r0 + rr;
        int id = logs[row];
        float x = (id == 0) ? 0.f : embed_val(id, col, meta, iW, bW, cW) * 9.797958971132712f;
        xs[rr][col] = x;
        red[g][col] = x;
        __syncthreads();
        for (int off = 64; off; off >>= 1) { if (col < off) red[g][col] += red[g][col+off]; __syncthreads(); }
        float mu = red[g][0] * (1.f/HID);
        __syncthreads();
        float c = x - mu;
        red[g][col] = c*c; __syncthreads();
        for (int off = 64; off; off >>= 1) { if (col < off) red[g][col] += red[g][col+off]; __syncthreads(); }
        float ln = c * rsqrtf(red[g][0]*(1.f/HID) + LNEPS) * lns[col] + lnb[col];
        qn[rr][col] = ln;
        Qn[(size_t)row*HID + col] = ln;
        __syncthreads();
    }

    int rA = 2*g, rB = 2*g + 1;
    float aq0 = Qb[col], aq1 = aq0;
    float ak0 = Kb[col], ak1 = ak0;
    float av0 = Vb[col], av1 = av0;
    const float* q0 = qn[rA]; const float* q1 = qn[rB];
    const float* x0 = xs[rA]; const float* x1 = xs[rB];
    #pragma unroll 8
    for (int kk = 0; kk < HID; ++kk) {
        float wq = Qw[kk*HID + col];
        float wk = Kw[kk*HID + col];
        float wv = Vw[kk*HID + col];
        aq0 += q0[kk]*wq; aq1 += q1[kk]*wq;
        ak0 += x0[kk]*wk; ak1 += x1[kk]*wk;
        av0 += x0[kk]*wv; av1 += x1[kk]*wv;
    }
    int rowA = r0 + rA, rowB = r0 + rB;
    int lA = rowA % LL, lB = rowB % LL;
    qbuf[(size_t)rowA*HID + col] = aq0;
    qbuf[(size_t)rowB*HID + col] = aq1;
    kbh[(size_t)rowA*HID + col] = f2h(ak0 + posK[lA*HID + col]);
    kbh[(size_t)rowB*HID + col] = f2h(ak1 + posK[lB*HID + col]);
    vbh[(size_t)rowA*HID + col] = f2h(av0 + posV[lA*HID + col]);
    vbh[(size_t)rowB*HID + col] = f2h(av1 + posV[lB*HID + col]);
}

// ---------------- attention: block=(h,i,bh), 8 waves; fp16, dot2 score, no swizzle
__global__ __launch_bounds__(512) void k_attn(
    const float*   __restrict__ q,
    const ushort4* __restrict__ kph,  // fp16 k+posK, [NROW][32] as ushort4
    const ushort4* __restrict__ vph,  // fp16 v+posV
    const float4*  __restrict__ Qn4,
    const ushort4* __restrict__ tkh4, // fp16 tables [257][32] as ushort4
    const ushort4* __restrict__ tvh4,
    const int* __restrict__ tmat, const int* __restrict__ logs,
    float4* __restrict__ out4)
{
    __shared__ ushort4 tk_lds[257*8];   // ~16.45 KiB
    __shared__ ushort4 tv_lds[257*8];   // (total ~32.9 KiB)

    int bid = blockIdx.x;
    int h   = bid & 3;
    int bh  = (bid >> 2) & 1;
    int i   = 199 - (bid >> 3);
    int tid = threadIdx.x;

    for (int e = tid; e < 257*8; e += 512) {
        int t = e >> 3, s = e & 7;
        tk_lds[t*8 + s] = tkh4[(size_t)t*32 + h*8 + s];
        tv_lds[t*8 + s] = tvh4[(size_t)t*32 + h*8 + s];
    }
    __syncthreads();

    int b = __builtin_amdgcn_readfirstlane(tid >> 6) + bh*8;
    int lane = tid & 63;
    int row = b*LL + i;
    int valid = (logs[row] != 0);
    int nj = valid ? (i + 1) : LL;

    int g8 = lane & 56;        // j-octet offset of this lane's group
    int d4 = lane & 7;         // ushort4-slice index within the 32-wide head dim

    float4 qq = ((const float4*)q)[(size_t)row*32 + h*8 + d4];
    h2s q01 = __builtin_amdgcn_cvt_pkrtz(qq.x, qq.y);
    h2s q23 = __builtin_amdgcn_cvt_pkrtz(qq.z, qq.w);

    int tsv[4];
    #pragma unroll
    for (int c = 0; c < 4; ++c) {
        int j = c*64 + lane;
        tsv[c] = (j < nj) ? tmat[(size_t)row*LL + j] : 0;
    }

    // scores (transposed): group handles j = c*64 + g8 + qi; 4 chained dot2 per lane
    float ev[4];
    #pragma unroll
    for (int c = 0; c < 4; ++c) {
        float s0 = -INFINITY;
        if (valid) {
            int jbase = c*64 + g8;
            if (jbase < nj) {
                #pragma unroll
                for (int qi = 0; qi < 8; ++qi) {
                    int j = jbase + qi;
                    bool ok = (j < nj);                  // uniform within the 8-lane group
                    int t = __shfl(tsv[c], g8 + qi);
                    float part = 0.f;
                    if (ok) {
                        U4 kr; kr.u = kph[((size_t)(b*LL + j))*32 + h*8 + d4];
                        U4 tk; tk.u = tk_lds[t*8 + d4];
                        part = __builtin_amdgcn_fdot2(q01, kr.h[0], 0.f,  false);
                        part = __builtin_amdgcn_fdot2(q23, kr.h[1], part, false);
                        part = __builtin_amdgcn_fdot2(q01, tk.h[0], part, false);
                        part = __builtin_amdgcn_fdot2(q23, tk.h[1], part, false);
                    }
                    part += __shfl_xor(part, 1);
                    part += __shfl_xor(part, 2);
                    part += __shfl_xor(part, 4);
                    if (qi == d4 && ok) s0 = part * 0.17677669529663687f;
                }
            }
        } else {
            if (c*64 + lane < nj) s0 = 0.f;              // invalid row -> uniform softmax
        }
        ev[c] = s0;
    }

    // softmax (in-register, wave-level)
    float m = fmaxf(fmaxf(ev[0], ev[1]), fmaxf(ev[2], ev[3]));
    #pragma unroll
    for (int off = 32; off; off >>= 1) m = fmaxf(m, __shfl_xor(m, off));
    float ssum = 0.f;
    #pragma unroll
    for (int c = 0; c < 4; ++c) {
        int j = c*64 + lane;
        float e = (j < nj) ? __expf(ev[c] - m) : 0.f;
        ev[c] = e; ssum += e;
    }
    #pragma unroll
    for (int off = 32; off; off >>= 1) ssum += __shfl_xor(ssum, off);
    float inv = 1.f / ssum;

    // PV: lanes = (jc in 0..7) x (d4 in 0..7); packed fp16 add, fp32 accumulate
    int jc = lane >> 3;
    float4 acc = {0.f, 0.f, 0.f, 0.f};
    #pragma unroll
    for (int c = 0; c < 4; ++c) {
        int jlo = c*64;
        int jhi = (jlo + 64 < nj) ? (jlo + 64) : nj;
        for (int jj = jlo; jj < jhi; jj += 8) {
            int j = jj + jc;
            float a  = __shfl(ev[c],  j & 63);
            int  tsj = __shfl(tsv[c], j & 63);
            if (j < jhi) {
                U4 vr; vr.u = vph[((size_t)(b*LL + j))*32 + h*8 + d4];
                U4 tv; tv.u = tv_lds[tsj*8 + d4];
                h2a s01 = toa(vr.h[0]) + toa(tv.h[0]);
                h2a s23 = toa(vr.h[1]) + toa(tv.h[1]);
                acc.x += a * (float)s01[0];
                acc.y += a * (float)s01[1];
                acc.z += a * (float)s23[0];
                acc.w += a * (float)s23[1];
            }
        }
    }
    #pragma unroll
    for (int off = 8; off < 64; off <<= 1) {
        acc.x += __shfl_xor(acc.x, off);
        acc.y += __shfl_xor(acc.y, off);
        acc.z += __shfl_xor(acc.z, off);
        acc.w += __shfl_xor(acc.w, off);
    }
    if (jc == 0) {
        float4 qn = Qn4[(size_t)row*32 + h*8 + d4];
        float4 o;
        o.x = qn.x + acc.x*inv;
        o.y = qn.y + acc.y*inv;
        o.z = qn.z + acc.z*inv;
        o.w = qn.w + acc.w*inv;
        out4[(size_t)row*32 + h*8 + d4] = o;
    }
}

// ---------------- fwd-LN + FFN + residual + mask, 8 rows/block (in-place on seqs)
__global__ __launch_bounds__(512) void k_ffn(
    const float* __restrict__ seqs_in,
    const float* __restrict__ lns, const float* __restrict__ lnb,
    const float* __restrict__ c1w, const float* __restrict__ c1b,
    const float* __restrict__ c2w, const float* __restrict__ c2b,
    const int* __restrict__ logs,
    float* __restrict__ seqs_out)
{
    __shared__ float xs[8][HID];
    __shared__ float h1[8][HID];
    __shared__ float red[4][HID];
    int tid = threadIdx.x;
    int g = tid >> 7, col = tid & 127;
    int r0 = blockIdx.x * 8;

    #pragma unroll
    for (int p = 0; p < 2; ++p) {
        int rr = g + p*4;
        int row = r0 + rr;
        float x = seqs_in[(size_t)row*HID + col];
        red[g][col] = x;
        __syncthreads();
        for (int off = 64; off; off >>= 1) { if (col < off) red[g][col] += red[g][col+off]; __syncthreads(); }
        float mu = red[g][0] * (1.f/HID);
        __syncthreads();
        float c = x - mu;
        red[g][col] = c*c; __syncthreads();
        for (int off = 64; off; off >>= 1) { if (col < off) red[g][col] += red[g][col+off]; __syncthreads(); }
        xs[rr][col] = c * rsqrtf(red[g][0]*(1.f/HID) + LNEPS) * lns[col] + lnb[col];
        __syncthreads();
    }

    int rA = 2*g, rB = 2*g + 1;
    {
        float a0 = c1b[col], a1 = a0;
        const float* x0 = xs[rA]; const float* x1 = xs[rB];
        #pragma unroll 8
        for (int kk = 0; kk < HID; ++kk) {
            float w = c1w[kk*HID + col];
            a0 += x0[kk]*w; a1 += x1[kk]*w;
        }
        h1[rA][col] = fmaxf(a0, 0.f);
        h1[rB][col] = fmaxf(a1, 0.f);
    }
    __syncthreads();

    {
        float a0 = c2b[col], a1 = a0;
        const float* y0 = h1[rA]; const float* y1 = h1[rB];
        #pragma unroll 8
        for (int kk = 0; kk < HID; ++kk) {
            float w = c2w[kk*HID + col];
            a0 += y0[kk]*w; a1 += y1[kk]*w;
        }
        int rowA = r0 + rA, rowB = r0 + rB;
        float o0 = xs[rA][col] + a0;
        float o1 = xs[rB][col] + a1;
        if (logs[rowA] == 0) o0 = 0.f;
        if (logs[rowB] == 0) o1 = 0.f;
        seqs_out[(size_t)rowA*HID + col] = o0;
        seqs_out[(size_t)rowB*HID + col] = o1;
    }
}

// ---------------- attn-LN + Q/K/V GEMVs, 8 rows/block
__global__ __launch_bounds__(512) void k_lnqkv(
    const float* __restrict__ seqs,
    const float* __restrict__ lns, const float* __restrict__ lnb,
    const float* __restrict__ Qw, const float* __restrict__ Qb,
    const float* __restrict__ Kw, const float* __restrict__ Kb,
    const float* __restrict__ Vw, const float* __restrict__ Vb,
    const float* __restrict__ posK, const float* __restrict__ posV,
    float* __restrict__ Qn, float* __restrict__ qbuf,
    ushort_t* __restrict__ kbh, ushort_t* __restrict__ vbh)
{
    __shared__ float xs[8][HID];
    __shared__ float qn[8][HID];
    __shared__ float red[4][HID];
    int tid = threadIdx.x;
    int g = tid >> 7, col = tid & 127;
    int r0 = blockIdx.x * 8;

    #pragma unroll
    for (int p = 0; p < 2; ++p) {
        int rr = g + p*4;
        int row = r0 + rr;
        float x = seqs[(size_t)row*HID + col];
        xs[rr][col] = x;
        red[g][col] = x;
        __syncthreads();
        for (int off = 64; off; off >>= 1) { if (col < off) red[g][col] += red[g][col+off]; __syncthreads(); }
        float mu = red[g][0] * (1.f/HID);
        __syncthreads();
        float c = x - mu;
        red[g][col] = c*c; __syncthreads();
        for (int off = 64; off; off >>= 1) { if (col < off) red[g][col] += red[g][col+off]; __syncthreads(); }
        float ln = c * rsqrtf(red[g][0]*(1.f/HID) + LNEPS) * lns[col] + lnb[col];
        qn[rr][col] = ln;
        Qn[(size_t)row*HID + col] = ln;
        __syncthreads();
    }

    int rA = 2*g, rB = 2*g + 1;
    float aq0 = Qb[col], aq1 = aq0;
    float ak0 = Kb[col], ak1 = ak0;
    float av0 = Vb[col], av1 = av0;
    const float* q0 = qn[rA]; const float* q1 = qn[rB];
    const float* x0 = xs[rA]; const float* x1 = xs[rB];
    #pragma unroll 8
    for (int kk = 0; kk < HID; ++kk) {
        float wq = Qw[kk*HID + col];
        float wk = Kw[kk*HID + col];
        float wv = Vw[kk*HID + col];
        aq0 += q0[kk]*wq; aq1 += q1[kk]*wq;
        ak0 += x0[kk]*wk; ak1 += x1[kk]*wk;
        av0 += x0[kk]*wv; av1 += x1[kk]*wv;
    }
    int rowA = r0 + rA, rowB = r0 + rB;
    int lA = rowA % LL, lB = rowB % LL;
    qbuf[(size_t)rowA*HID + col] = aq0;
    qbuf[(size_t)rowB*HID + col] = aq1;
    kbh[(size_t)rowA*HID + col] = f2h(ak0 + posK[lA*HID + col]);
    kbh[(size_t)rowB*HID + col] = f2h(ak1 + posK[lB*HID + col]);
    vbh[(size_t)rowA*HID + col] = f2h(av0 + posV[lA*HID + col]);
    vbh[(size_t)rowB*HID + col] = f2h(av1 + posV[lB*HID + col]);
}

// ---------------- K3: FFN(1) + last-LN + pos/neg logits, 8 rows/block
__global__ __launch_bounds__(512) void k_ffn_logits(
    const float* __restrict__ seqs_in,
    const float* __restrict__ flns, const float* __restrict__ flnb,
    const float* __restrict__ c1w, const float* __restrict__ c1b,
    const float* __restrict__ c2w, const float* __restrict__ c2b,
    const int* __restrict__ logs,
    const float* __restrict__ lls, const float* __restrict__ llb,
    const int* __restrict__ pos, const int* __restrict__ neg,
    const int* __restrict__ meta,
    const float* __restrict__ iW, const float* __restrict__ bW,
    const float* __restrict__ cW,
    float* __restrict__ out)
{
    __shared__ float xs[8][HID];
    __shared__ float h1[8][HID];
    __shared__ float red[4][HID];
    __shared__ float sx[8][HID];
    int tid = threadIdx.x;
    int g = tid >> 7, col = tid & 127;
    int r0 = blockIdx.x * 8;

    #pragma unroll
    for (int p = 0; p < 2; ++p) {
        int rr = g + p*4;
        int row = r0 + rr;
        float x = seqs_in[(size_t)row*HID + col];
        red[g][col] = x;
        __syncthreads();
        for (int off = 64; off; off >>= 1) { if (col < off) red[g][col] += red[g][col+off]; __syncthreads(); }
        float mu = red[g][0] * (1.f/HID);
        __syncthreads();
        float c = x - mu;
        red[g][col] = c*c; __syncthreads();
        for (int off = 64; off; off >>= 1) { if (col < off) red[g][col] += red[g][col+off]; __syncthreads(); }
        xs[rr][col] = c * rsqrtf(red[g][0]*(1.f/HID) + LNEPS) * flns[col] + flnb[col];
        __syncthreads();
    }

    int rA = 2*g, rB = 2*g + 1;
    {
        float a0 = c1b[col], a1 = a0;
        const float* x0 = xs[rA]; const float* x1 = xs[rB];
        #pragma unroll 8
        for (int kk = 0; kk < HID; ++kk) {
            float w = c1w[kk*HID + col];
            a0 += x0[kk]*w; a1 += x1[kk]*w;
        }
        h1[rA][col] = fmaxf(a0, 0.f);
        h1[rB][col] = fmaxf(a1, 0.f);
    }
    __syncthreads();
    {
        float a0 = c2b[col], a1 = a0;
        const float* y0 = h1[rA]; const float* y1 = h1[rB];
        #pragma unroll 8
        for (int kk = 0; kk < HID; ++kk) {
            float w = c2w[kk*HID + col];
            a0 += y0[kk]*w; a1 += y1[kk]*w;
        }
        int rowA = r0 + rA, rowB = r0 + rB;
        float o0 = xs[rA][col] + a0;
        float o1 = xs[rB][col] + a1;
        if (logs[rowA] == 0) o0 = 0.f;
        if (logs[rowB] == 0) o1 = 0.f;
        sx[rA][col] = o0;
        sx[rB][col] = o1;
    }
    __syncthreads();

    #pragma unroll
    for (int p = 0; p < 2; ++p) {
        int rr = g + p*4;
        int row = r0 + rr;
        float x = sx[rr][col];
        red[g][col] = x;
        __syncthreads();
        for (int off = 64; off; off >>= 1) { if (col < off) red[g][col] += red[g][col+off]; __syncthreads(); }
        float mu = red[g][0] * (1.f/HID);
        __syncthreads();
        float c = x - mu;
        red[g][col] = c*c; __syncthreads();
        for (int off = 64; off; off >>= 1) { if (col < off) red[g][col] += red[g][col+off]; __syncthreads(); }
        float f = c * rsqrtf(red[g][0]*(1.f/HID) + LNEPS) * lls[col] + llb[col];
        __syncthreads();

        int pid = pos[row];
        float e = embed_val(pid, col, meta, iW, bW, cW);
        red[g][col] = f * e; __syncthreads();
        for (int off = 64; off; off >>= 1) { if (col < off) red[g][col] += red[g][col+off]; __syncthreads(); }
        if (col == 0) out[row] = red[g][0];
        __syncthreads();

        int nid = neg[row];
        e = embed_val(nid, col, meta, iW, bW, cW);
        red[g][col] = f * e; __syncthreads();
        for (int off = 64; off; off >>= 1) { if (col < off) red[g][col] += red[g][col+off]; __syncthreads(); }
        if (col == 0) out[NROW + row] = red[g][0];
        __syncthreads();
    }
}

extern "C" void kernel_launch(void* const* d_in, const int* in_sizes, int n_in,
                              void* d_out, int out_size, void* d_ws, size_t ws_size,
                              hipStream_t stream)
{
    const int*  logs = (const int*)d_in[1];
    const int*  tmat = (const int*)d_in[2];
    const int*  pos  = (const int*)d_in[3];
    const int*  neg  = (const int*)d_in[4];
    const int*  meta = (const int*)d_in[5];
    const float* iW   = (const float*)d_in[6];
    const float* bW   = (const float*)d_in[7];
    const float* cW   = (const float*)d_in[8];
    const float* posK = (const float*)d_in[9];
    const float* posV = (const float*)d_in[10];
    const float* tK   = (const float*)d_in[11];
    const float* tV   = (const float*)d_in[12];
    const float* attn_s = (const float*)d_in[13];
    const float* attn_b = (const float*)d_in[14];
    const float* Qw = (const float*)d_in[15];
    const float* Qb = (const float*)d_in[16];
    const float* Kw = (const float*)d_in[17];
    const float* Kb = (const float*)d_in[18];
    const float* Vw = (const float*)d_in[19];
    const float* Vb = (const float*)d_in[20];
    const float* fwd_s = (const float*)d_in[21];
    const float* fwd_b = (const float*)d_in[22];
    const float* c1w = (const float*)d_in[23];
    const float* c1b = (const float*)d_in[24];
    const float* c2w = (const float*)d_in[25];
    const float* c2b = (const float*)d_in[26];
    const float* lls = (const float*)d_in[27];
    const float* llb = (const float*)d_in[28];

    const size_t RC = (size_t)NROW * HID;
    float* seqs = (float*)d_ws;
    float* Qn   = seqs + RC;
    float* qbuf = Qn   + RC;
    ushort_t* kbh = (ushort_t*)(qbuf + RC);            // [NROW][128] fp16
    ushort_t* vbh = kbh + RC;
    ushort_t* tkh = vbh + RC;                          // [257][128] fp16
    ushort_t* tvh = tkh + 257*HID;

    const size_t W = (size_t)HID * HID;

    // layer 0 (also converts tK/tV tables to fp16)
    k_emb_lnqkv<<<NROW/8, 512, 0, stream>>>(logs, meta, iW, bW, cW,
                                            attn_s, attn_b,
                                            Qw, Qb, Kw, Kb, Vw, Vb,
                                            posK, posV, tK, tV, tkh, tvh,
                                            Qn, qbuf, kbh, vbh);
    k_attn<<<NH*LL*2, 512, 0, stream>>>(qbuf, (const ushort4*)kbh,
                                        (const ushort4*)vbh, (const float4*)Qn,
                                        (const ushort4*)tkh, (const ushort4*)tvh,
                                        tmat, logs, (float4*)seqs);
    k_ffn<<<NROW/8, 512, 0, stream>>>(seqs, fwd_s, fwd_b,
                                      c1w, c1b, c2w, c2b, logs, seqs);
    // layer 1
    k_lnqkv<<<NROW/8, 512, 0, stream>>>(seqs, attn_s + HID, attn_b + HID,
                                        Qw + W, Qb + HID, Kw + W, Kb + HID,
                                        Vw + W, Vb + HID,
                                        posK, posV, Qn, qbuf, kbh, vbh);
    k_attn<<<NH*LL*2, 512, 0, stream>>>(qbuf, (const ushort4*)kbh,
                                        (const ushort4*)vbh, (const float4*)Qn,
                                        (const ushort4*)tkh, (const ushort4*)tvh,
                                        tmat, logs, (float4*)seqs);
    k_ffn_logits<<<NROW/8, 512, 0, stream>>>(seqs, fwd_s + HID, fwd_b + HID,
                                             c1w + W, c1b + HID, c2w + W, c2b + HID,
                                             logs, lls, llb, pos, neg, meta,
                                             iW, bW, cW, (float*)d_out);
}